// Round 1
// 421.691 us; speedup vs baseline: 1.0531x; 1.0531x over previous
//
#include <hip/hip_runtime.h>
#include <stdint.h>

#define LDK 136   // padded LDS K-stride (shorts): byte stride 272 -> b128 frag reads spread 8 lanes/4-bank group

typedef __attribute__((ext_vector_type(4))) float f32x4;
typedef __attribute__((ext_vector_type(8))) short bf16x8;

__device__ inline unsigned short f2bf_rtne(float f) {
    union { float f; unsigned u; } v; v.f = f;
    unsigned u = v.u;
    u += 0x7fffu + ((u >> 16) & 1u);
    return (unsigned short)(u >> 16);
}

// ---------------------------------------------------------------------------
// prep: weight transpose+bf16 cast (W1,W2 -> [n][k]; W3 -> padded 16x128 A-layout),
// mask decode, num_atoms, per-64-j-group "any unmasked" flags, out zero-init.
// grid: 64 blocks x 256.
// ---------------------------------------------------------------------------
__global__ void prep_kernel(const float* __restrict__ relW1, const float* __restrict__ relW2,
                            const float* __restrict__ pwW1, const float* __restrict__ pwW2,
                            const float* __restrict__ relW3, const float* __restrict__ pwW3,
                            const void* __restrict__ maskp,
                            float* __restrict__ maskf, float* __restrict__ na,
                            int* __restrict__ gflag, float* __restrict__ out,
                            unsigned short* __restrict__ w1T_rel, unsigned short* __restrict__ w2T_rel,
                            unsigned short* __restrict__ w1T_pw, unsigned short* __restrict__ w2T_pw,
                            unsigned short* __restrict__ w3T_rel, unsigned short* __restrict__ w3T_pw) {
    int t = threadIdx.x;
    const float* srcs[4] = {relW1, relW2, pwW1, pwW2};
    unsigned short* dsts[4] = {w1T_rel, w2T_rel, w1T_pw, w2T_pw};
    int e0 = blockIdx.x * 1024 + t;
#pragma unroll
    for (int i = 0; i < 4; ++i) {
        int e = e0 + i * 256;
        int mat = e >> 14, o = e & 16383;
        int n = o >> 7, k = o & 127;
        dsts[mat][o] = f2bf_rtne(srcs[mat][k * 128 + n]);   // wT[n][k] = W[k][n]
    }
    if (blockIdx.x == 1) {
        // W3^T padded to 16 rows x 128 cols (rows 4..15 zero), bf16
        for (int i = t; i < 2048; i += 256) {
            int r = i >> 7, h = i & 127;
            w3T_rel[i] = (r < 4) ? f2bf_rtne(relW3[h * 4 + r]) : (unsigned short)0;
            w3T_pw[i]  = (r < 4) ? f2bf_rtne(pwW3[h * 4 + r])  : (unsigned short)0;
        }
    }
    if (blockIdx.x == 2) {
        // out is accumulated atomically by mlp_kernel -> zero-init each launch
        for (int i = t; i < 3072; i += 256) out[i] = 0.f;
    }
    if (blockIdx.x == 0) {
        __shared__ int anyb;
        __shared__ float cnt[2];
        if (t == 0) anyb = 0;
        if (t < 2) cnt[t] = 0.f;
        __syncthreads();
        // robust mask dtype detection: bool8 storage has nonzero bytes within the
        // first 1024 bytes (indices 448..511 true); int32 storage is all-zero there.
        const unsigned char* mb = (const unsigned char*)maskp;
        int la = 0;
        for (int i = t; i < 1024; i += 256) la |= mb[i];
        if (la) atomicOr(&anyb, 1);
        __syncthreads();
        bool isbyte = (anyb != 0);
        const int* mi = (const int*)maskp;
        float loc0 = 0.f, loc1 = 0.f;
        for (int i = t; i < 1024; i += 256) {
            int v = isbyte ? (int)mb[i] : mi[i];
            float um = (v != 0) ? 0.f : 1.f;   // unmasked = !masked
            maskf[i] = um;
            if (i < 512) loc0 += um; else loc1 += um;
        }
        atomicAdd(&cnt[0], loc0);
        atomicAdd(&cnt[1], loc1);
        __syncthreads();
        if (t < 2) na[t] = cnt[t];
        if (t < 16) {
            // group g = (b, 64-j window): any unmasked j? (fully-masked tiles are skippable)
            float s = 0.f;
            for (int j = 0; j < 64; ++j) s += maskf[t * 64 + j];
            gflag[t] = (s > 0.f) ? 1 : 0;
        }
    }
}

// ---------------------------------------------------------------------------
// fused 3-layer MLP + basis reduction:
//   blocks 0..3      : pointwise rows (B*N=1024), epilogue -> atomicAdd out*(1/na)
//   blocks 4..2051   : relative rows (B*N*N),   S -> LDS -> per-thread (row,k)
//                      partials vs prefetched basis -> shuffle reduce ->
//                      3 atomicAdds/block of partial*(1/na^2)
// Fully-masked 64-row j-tiles are skipped (block-uniform, via gflag).
// Single xs buffer (register px prefetch), single hs buffer, 4 barriers/tile.
// ---------------------------------------------------------------------------
__global__ __launch_bounds__(256, 2)
void mlp_kernel(const float* __restrict__ Xrel, const float* __restrict__ Xpw,
                const unsigned short* __restrict__ w1Tr, const unsigned short* __restrict__ w2Tr,
                const unsigned short* __restrict__ w3Tr,
                const unsigned short* __restrict__ w1Tp, const unsigned short* __restrict__ w2Tp,
                const unsigned short* __restrict__ w3Tp,
                const float* __restrict__ b1r, const float* __restrict__ b2r, const float* __restrict__ b3r,
                const float* __restrict__ b1p, const float* __restrict__ b2p, const float* __restrict__ b3p,
                const float* __restrict__ rel_basis, const float* __restrict__ pw_basis,
                const float* __restrict__ maskf, const float* __restrict__ na,
                const int* __restrict__ gflag,
                float* __restrict__ out) {
    __shared__ short xs[64 * LDK];
    __shared__ short hs[64 * LDK];
    __shared__ float bs1[128], bs2[128], b3s[4];
    __shared__ float Sl[256];        // 64 rows x 4 scales (masked)
    __shared__ float red[4][4][3];   // wave x k x coord

    int t = threadIdx.x;
    int w = t >> 6, lane = t & 63, q = lane >> 4, col = lane & 15;

    bool isrel = (blockIdx.x >= 4);
    int rb = isrel ? ((int)blockIdx.x - 4) : (int)blockIdx.x;

    const float* X = isrel ? Xrel : Xpw;
    const unsigned short* w1T = isrel ? w1Tr : w1Tp;
    const unsigned short* w2T = isrel ? w2Tr : w2Tp;
    const unsigned short* w3T = isrel ? w3Tr : w3Tp;
    const float* b1 = isrel ? b1r : b1p;
    const float* b2 = isrel ? b2r : b2p;
    const float* b3 = isrel ? b3r : b3p;

    if (t < 128) { bs1[t] = b1[t]; bs2[t] = b2[t]; }
    if (t < 4) b3s[t] = b3[t];

    int b = isrel ? (rb >> 10) : (rb >> 1);
    float NA = na[b];
    float scale = isrel ? (1.f / (NA * NA)) : (1.f / NA);

    // active-tile nibble pack (no runtime-indexed array -> stays in registers)
    int apack = 0x3210, nact = 4;
    if (isrel) {
        apack = 0; nact = 0;
        int gbase = b * 8 + (rb & 1) * 4;
#pragma unroll
        for (int tt = 0; tt < 4; ++tt)
            if (gflag[gbase + tt]) { apack |= tt << (4 * nact); ++nact; }
        if (nact == 0) return;   // uniform: whole block exits before any barrier
    }

    // A-operand (weight) fragments: A[n][k], n = base+(lane&15), k = kc*32+(lane>>4)*8+j
    bf16x8 w1f[2][4], w2f[2][4], w3f[4];
#pragma unroll
    for (int tn = 0; tn < 2; ++tn)
#pragma unroll
        for (int kc = 0; kc < 4; ++kc) {
            int n = w * 32 + tn * 16 + col;
            int kk = kc * 32 + q * 8;
            w1f[tn][kc] = *(const bf16x8*)&w1T[n * 128 + kk];
            w2f[tn][kc] = *(const bf16x8*)&w2T[n * 128 + kk];
        }
#pragma unroll
    for (int kc = 0; kc < 4; ++kc)
        w3f[kc] = *(const bf16x8*)&w3T[col * 128 + kc * 32 + q * 8];

    long rowbase = (long)rb * 256;
    int r0 = t >> 5, cg = t & 31;
    int arow = t >> 2, ak = t & 3;   // reduction mapping: thread -> (tile row, k)

    float4 px[8];
    {
        const float4* Xg = (const float4*)(X + (rowbase + (long)(apack & 15) * 64) * 128);
#pragma unroll
        for (int i = 0; i < 8; ++i) px[i] = Xg[(r0 + 8 * i) * 32 + cg];
#pragma unroll
        for (int i = 0; i < 8; ++i) {
            float4 v = px[i];
            short4 s4 = make_short4((short)f2bf_rtne(v.x), (short)f2bf_rtne(v.y),
                                    (short)f2bf_rtne(v.z), (short)f2bf_rtne(v.w));
            *(short4*)&xs[(r0 + 8 * i) * LDK + cg * 4] = s4;
        }
    }
    __syncthreads();

    float p0 = 0.f, p1 = 0.f, p2 = 0.f;

    for (int a = 0; a < nact; ++a) {
        int tile = (apack >> (4 * a)) & 15;
        long trow = rowbase + (long)tile * 64;

        if (a + 1 < nact) {  // prefetch next active X tile into regs (cover = layer1 + epi1)
            int tnx = (apack >> (4 * (a + 1))) & 15;
            const float4* Xg2 = (const float4*)(X + (rowbase + (long)tnx * 64) * 128);
#pragma unroll
            for (int i = 0; i < 8; ++i) px[i] = Xg2[(r0 + 8 * i) * 32 + cg];
        }

        // prefetch this tile's basis (3 floats/thread) + mask row early; used post-L3
        float bas0 = 0.f, bas1 = 0.f, bas2 = 0.f, mrow = 0.f;
        if (isrel) {
            const float* bp = &rel_basis[(trow + arow) * 12 + ak * 3];
            bas0 = bp[0]; bas1 = bp[1]; bas2 = bp[2];
            mrow = maskf[b * 512 + (rb & 1) * 256 + tile * 64 + w * 16 + col];
        }

        // ---- layer 1: D = W1^T · X^T ----
        f32x4 acc[2][4];
#pragma unroll
        for (int tn = 0; tn < 2; ++tn)
#pragma unroll
            for (int tm = 0; tm < 4; ++tm) acc[tn][tm] = (f32x4)(0.f);
#pragma unroll
        for (int kc = 0; kc < 4; ++kc) {
            bf16x8 bf[4];
#pragma unroll
            for (int tm = 0; tm < 4; ++tm)
                bf[tm] = *(const bf16x8*)&xs[(tm * 16 + col) * LDK + kc * 32 + q * 8];
#pragma unroll
            for (int tn = 0; tn < 2; ++tn)
#pragma unroll
                for (int tm = 0; tm < 4; ++tm)
                    acc[tn][tm] = __builtin_amdgcn_mfma_f32_16x16x32_bf16(w1f[tn][kc], bf[tm], acc[tn][tm], 0, 0, 0);
        }

        // epilogue 1: bias+relu -> bf16 -> hs (prev reader was this tile-1's L3; fenced by E)
#pragma unroll
        for (int tn = 0; tn < 2; ++tn)
#pragma unroll
            for (int tm = 0; tm < 4; ++tm) {
                int n0 = w * 32 + tn * 16 + q * 4;
                int m = tm * 16 + col;
                float4 bb = *(const float4*)&bs1[n0];
                short4 s4 = make_short4(
                    (short)f2bf_rtne(fmaxf(acc[tn][tm][0] + bb.x, 0.f)),
                    (short)f2bf_rtne(fmaxf(acc[tn][tm][1] + bb.y, 0.f)),
                    (short)f2bf_rtne(fmaxf(acc[tn][tm][2] + bb.z, 0.f)),
                    (short)f2bf_rtne(fmaxf(acc[tn][tm][3] + bb.w, 0.f)));
                *(short4*)&hs[m * LDK + n0] = s4;
            }
        __syncthreads();  // AB: xs reads done (can restage) + hs H1 visible

        if (a + 1 < nact) {  // stage prefetched X into (single) xs buffer
#pragma unroll
            for (int i = 0; i < 8; ++i) {
                float4 v = px[i];
                short4 s4 = make_short4((short)f2bf_rtne(v.x), (short)f2bf_rtne(v.y),
                                        (short)f2bf_rtne(v.z), (short)f2bf_rtne(v.w));
                *(short4*)&xs[(r0 + 8 * i) * LDK + cg * 4] = s4;
            }
        }

        // ---- layer 2: D = W2^T · H1^T ----
        f32x4 acc2[2][4];
#pragma unroll
        for (int tn = 0; tn < 2; ++tn)
#pragma unroll
            for (int tm = 0; tm < 4; ++tm) acc2[tn][tm] = (f32x4)(0.f);
#pragma unroll
        for (int kc = 0; kc < 4; ++kc) {
            bf16x8 bf[4];
#pragma unroll
            for (int tm = 0; tm < 4; ++tm)
                bf[tm] = *(const bf16x8*)&hs[(tm * 16 + col) * LDK + kc * 32 + q * 8];
#pragma unroll
            for (int tn = 0; tn < 2; ++tn)
#pragma unroll
                for (int tm = 0; tm < 4; ++tm)
                    acc2[tn][tm] = __builtin_amdgcn_mfma_f32_16x16x32_bf16(w2f[tn][kc], bf[tm], acc2[tn][tm], 0, 0, 0);
        }
        __syncthreads();  // C: hs H1 reads done, may overwrite

        // epilogue 2 -> hs = H2
#pragma unroll
        for (int tn = 0; tn < 2; ++tn)
#pragma unroll
            for (int tm = 0; tm < 4; ++tm) {
                int n0 = w * 32 + tn * 16 + q * 4;
                int m = tm * 16 + col;
                float4 bb = *(const float4*)&bs2[n0];
                short4 s4 = make_short4(
                    (short)f2bf_rtne(fmaxf(acc2[tn][tm][0] + bb.x, 0.f)),
                    (short)f2bf_rtne(fmaxf(acc2[tn][tm][1] + bb.y, 0.f)),
                    (short)f2bf_rtne(fmaxf(acc2[tn][tm][2] + bb.z, 0.f)),
                    (short)f2bf_rtne(fmaxf(acc2[tn][tm][3] + bb.w, 0.f)));
                *(short4*)&hs[m * LDK + n0] = s4;
            }
        __syncthreads();  // D: H2 visible

        // ---- layer 3: D = W3pad^T · H2^T (4 MFMAs/wave; wave w owns rows w*16..) ----
        {
            f32x4 a3 = (f32x4)(0.f);
#pragma unroll
            for (int kc = 0; kc < 4; ++kc) {
                bf16x8 hb = *(const bf16x8*)&hs[(w * 16 + col) * LDK + kc * 32 + q * 8];
                a3 = __builtin_amdgcn_mfma_f32_16x16x32_bf16(w3f[kc], hb, a3, 0, 0, 0);
            }
            if (isrel) {
                if (q == 0) {   // a3[k] = S[k][row], row = w*16+col; fold mask here
                    float4 sm = make_float4((a3[0] + b3s[0]) * mrow, (a3[1] + b3s[1]) * mrow,
                                            (a3[2] + b3s[2]) * mrow, (a3[3] + b3s[3]) * mrow);
                    *(float4*)&Sl[(w * 16 + col) * 4] = sm;
                }
            } else if (q == 0) {
                // pointwise: out[bi,c] += (sum_k S[k]*pwb[k,c]) / na
                long bi = trow + w * 16 + col;
                float s0 = a3[0] + b3s[0], s1 = a3[1] + b3s[1];
                float s2 = a3[2] + b3s[2], s3 = a3[3] + b3s[3];
                const float* pbp = &pw_basis[bi * 12];
                float o0 = s0 * pbp[0] + s1 * pbp[3] + s2 * pbp[6] + s3 * pbp[9];
                float o1 = s0 * pbp[1] + s1 * pbp[4] + s2 * pbp[7] + s3 * pbp[10];
                float o2 = s0 * pbp[2] + s1 * pbp[5] + s2 * pbp[8] + s3 * pbp[11];
                atomicAdd(&out[bi * 3 + 0], o0 * scale);
                atomicAdd(&out[bi * 3 + 1], o1 * scale);
                atomicAdd(&out[bi * 3 + 2], o2 * scale);
            }
        }
        __syncthreads();  // E: Sl visible; also fences hs L3-reads vs next epi1 writes

        if (isrel) {
            // thread (arow, ak): p_c += S[arow][ak] * basis[arow][ak][c]
            float sk = Sl[arow * 4 + ak];
            p0 += sk * bas0; p1 += sk * bas1; p2 += sk * bas2;
        }
    }

    if (isrel) {
        // reduce over rows (lanes with same k = lane&3), then waves, then k
#pragma unroll
        for (int s = 32; s >= 4; s >>= 1) {
            p0 += __shfl_down(p0, s);
            p1 += __shfl_down(p1, s);
            p2 += __shfl_down(p2, s);
        }
        if (lane < 4) { red[w][lane][0] = p0; red[w][lane][1] = p1; red[w][lane][2] = p2; }
        __syncthreads();
        if (t < 3) {
            float v = 0.f;
#pragma unroll
            for (int ww = 0; ww < 4; ++ww)
#pragma unroll
                for (int k = 0; k < 4; ++k) v += red[ww][k][t];
            atomicAdd(&out[(long)(rb >> 1) * 3 + t], v * scale);   // scale = 1/na^2
        }
    }
}

// ---------------------------------------------------------------------------
extern "C" void kernel_launch(void* const* d_in, const int* in_sizes, int n_in,
                              void* d_out, int out_size, void* d_ws, size_t ws_size,
                              hipStream_t stream) {
    const float* pw_feat   = (const float*)d_in[0];
    const float* rel_feat  = (const float*)d_in[1];
    const float* pw_basis  = (const float*)d_in[2];
    const float* rel_basis = (const float*)d_in[3];
    const float* pw_W1 = (const float*)d_in[4];
    const float* pw_b1 = (const float*)d_in[5];
    const float* pw_W2 = (const float*)d_in[6];
    const float* pw_b2 = (const float*)d_in[7];
    const float* pw_W3 = (const float*)d_in[8];
    const float* pw_b3 = (const float*)d_in[9];
    const float* rel_W1 = (const float*)d_in[10];
    const float* rel_b1 = (const float*)d_in[11];
    const float* rel_W2 = (const float*)d_in[12];
    const float* rel_b2 = (const float*)d_in[13];
    const float* rel_W3 = (const float*)d_in[14];
    const float* rel_b3 = (const float*)d_in[15];
    const void*  maskp  = d_in[16];
    float* out = (float*)d_out;

    char* ws = (char*)d_ws;
    float* maskf = (float*)(ws + 0);                       // 1024 f32
    float* na    = (float*)(ws + 4096);                    // 2 f32
    int*   gflag = (int*)(ws + 4160);                      // 16 i32
    unsigned short* w1T_rel = (unsigned short*)(ws + 4352);
    unsigned short* w2T_rel = (unsigned short*)(ws + 37120);
    unsigned short* w1T_pw  = (unsigned short*)(ws + 69888);
    unsigned short* w2T_pw  = (unsigned short*)(ws + 102656);
    unsigned short* w3T_rel = (unsigned short*)(ws + 135424);  // 16x128 bf16
    unsigned short* w3T_pw  = (unsigned short*)(ws + 139520);

    prep_kernel<<<64, 256, 0, stream>>>(rel_W1, rel_W2, pw_W1, pw_W2, rel_W3, pw_W3, maskp,
                                        maskf, na, gflag, out,
                                        w1T_rel, w2T_rel, w1T_pw, w2T_pw,
                                        w3T_rel, w3T_pw);
    mlp_kernel<<<2052, 256, 0, stream>>>(rel_feat, pw_feat,
                                         w1T_rel, w2T_rel, w3T_rel,
                                         w1T_pw, w2T_pw, w3T_pw,
                                         rel_b1, rel_b2, rel_b3,
                                         pw_b1, pw_b2, pw_b3,
                                         rel_basis, pw_basis, maskf, na, gflag, out);
}